// Round 2
// baseline (816.924 us; speedup 1.0000x reference)
//
#include <hip/hip_runtime.h>
#include <hip/hip_bf16.h>

#define NN 4096
#define FIN 512
#define FOUT 64
#define NH 8
#define ALPHA 0.2f

typedef unsigned int uint;
typedef unsigned short ushort;

__device__ __forceinline__ float bflo(uint u) { return __uint_as_float(u << 16); }
__device__ __forceinline__ float bfhi(uint u) { return __uint_as_float(u & 0xffff0000u); }
__device__ __forceinline__ float bf2f(ushort s) { return __uint_as_float(((uint)s) << 16); }
__device__ __forceinline__ ushort f2bf(float f) {
    uint u = __float_as_uint(f);
    u += 0x7fffu + ((u >> 16) & 1u);   // round-to-nearest-even
    return (ushort)(u >> 16);
}

// ---------------------------------------------------------------------------
// Dtype probe: even (low-ushort) elements of a bf16 buffer are genuine values;
// of an fp32 buffer they are mantissa garbage. flag=1 -> bf16, flag=0 -> fp32.
// ---------------------------------------------------------------------------
__global__ void detect_kernel(const ushort* __restrict__ hraw, int* __restrict__ flag) {
    __shared__ int cnt[256];
    int t = threadIdx.x;
    float v = bf2f(hraw[2 * t]);
    float a = fabsf(v);
    cnt[t] = (a >= 1e-3f && a <= 100.0f) ? 1 : 0;   // NaN -> 0
    __syncthreads();
    for (int s = 128; s >= 1; s >>= 1) {
        if (t < s) cnt[t] += cnt[t + s];
        __syncthreads();
    }
    if (t == 0) *flag = (cnt[0] >= 128) ? 1 : 0;
}

// Convert one float tensor (fp32 or bf16 per flag) to bf16 in workspace.
__global__ void convert_kernel(const void* __restrict__ src, ushort* __restrict__ dst,
                               int n, const int* __restrict__ flag) {
    int i = blockIdx.x * 256 + threadIdx.x;
    if (i >= n) return;
    if (*flag)
        dst[i] = ((const ushort*)src)[i];
    else
        dst[i] = f2bf(((const float*)src)[i]);
}

// ---------------------------------------------------------------------------
// Stage 1: Wh[h,n,o] = sum_k h[n,k] * W[h,k,o] + bW[h,o]   (fp32 accumulate)
//          el[h,n] = Wh.a_l;  er'[h,n] = Wh.a_r + bA[h]
// ---------------------------------------------------------------------------
__global__ __launch_bounds__(256) void wh_kernel(
    const ushort* __restrict__ hmat,   // [N][FIN] bf16 (ws)
    const ushort* __restrict__ Wmat,   // [H][FIN][FOUT] bf16 (ws)
    const ushort* __restrict__ bW,
    const ushort* __restrict__ a_l,
    const ushort* __restrict__ a_r,
    const ushort* __restrict__ bA,
    float* __restrict__ Wh,            // [H][N][FOUT]
    float* __restrict__ el,            // [H][N]
    float* __restrict__ er)            // [H][N]
{
    __shared__ uint   sH[64][68];      // 64 rows x 64 k-pairs (bf16x2)
    __shared__ ushort sW[128][64];     // 128 k x 64 c
    __shared__ float  sEl[64], sEr[64];

    const int t     = threadIdx.x;
    const int head  = blockIdx.y;
    const int rbase = blockIdx.x * 64;

    const int r0 = (t >> 4) * 4;
    const int c0 = (t & 15) * 4;

    float acc[4][4];
#pragma unroll
    for (int a = 0; a < 4; a++)
#pragma unroll
        for (int b = 0; b < 4; b++) acc[a][b] = 0.f;

    for (int k0 = 0; k0 < FIN; k0 += 128) {
#pragma unroll
        for (int it = 0; it < 4; it++) {
            int id = it * 256 + t;
            int r = id >> 4, q = id & 15;
            uint4 v = *(const uint4*)(hmat + (size_t)(rbase + r) * FIN + k0 + q * 8);
            *(uint4*)(&sH[r][q * 4]) = v;
        }
#pragma unroll
        for (int it = 0; it < 4; it++) {
            int id = it * 256 + t;
            int kk = id >> 3, q = id & 7;
            uint4 v = *(const uint4*)(Wmat + (size_t)head * FIN * FOUT +
                                      (size_t)(k0 + kk) * FOUT + q * 8);
            *(uint4*)(&sW[kk][q * 8]) = v;
        }
        __syncthreads();

#pragma unroll 4
        for (int kp = 0; kp < 64; kp++) {
            uint hv[4] = { sH[r0 + 0][kp], sH[r0 + 1][kp], sH[r0 + 2][kp], sH[r0 + 3][kp] };
            uint2 w0 = *(const uint2*)(&sW[2 * kp + 0][c0]);
            uint2 w1 = *(const uint2*)(&sW[2 * kp + 1][c0]);
            float wA[4] = { bflo(w0.x), bfhi(w0.x), bflo(w0.y), bfhi(w0.y) };
            float wB[4] = { bflo(w1.x), bfhi(w1.x), bflo(w1.y), bfhi(w1.y) };
#pragma unroll
            for (int a = 0; a < 4; a++) {
                float xlo = bflo(hv[a]);
                float xhi = bfhi(hv[a]);
#pragma unroll
                for (int b = 0; b < 4; b++)
                    acc[a][b] = fmaf(xlo, wA[b], fmaf(xhi, wB[b], acc[a][b]));
            }
        }
        __syncthreads();
    }

    float al[4], ar[4], bw[4];
#pragma unroll
    for (int b = 0; b < 4; b++) {
        al[b] = bf2f(a_l[head * FOUT + c0 + b]);
        ar[b] = bf2f(a_r[head * FOUT + c0 + b]);
        bw[b] = bf2f(bW[head * FOUT + c0 + b]);
    }
    float pl[4] = {0.f, 0.f, 0.f, 0.f}, pr[4] = {0.f, 0.f, 0.f, 0.f};
#pragma unroll
    for (int a = 0; a < 4; a++) {
#pragma unroll
        for (int b = 0; b < 4; b++) {
            acc[a][b] += bw[b];
            pl[a] = fmaf(acc[a][b], al[b], pl[a]);
            pr[a] = fmaf(acc[a][b], ar[b], pr[a]);
        }
        *(float4*)(&Wh[((size_t)head * NN + rbase + r0 + a) * FOUT + c0]) =
            make_float4(acc[a][0], acc[a][1], acc[a][2], acc[a][3]);
    }
#pragma unroll
    for (int off = 1; off < 16; off <<= 1) {
#pragma unroll
        for (int a = 0; a < 4; a++) {
            pl[a] += __shfl_xor(pl[a], off);
            pr[a] += __shfl_xor(pr[a], off);
        }
    }
    if ((t & 15) == 0) {
#pragma unroll
        for (int a = 0; a < 4; a++) { sEl[r0 + a] = pl[a]; sEr[r0 + a] = pr[a]; }
    }
    __syncthreads();
    if (t < 64) {
        el[(size_t)head * NN + rbase + t] = sEl[t];
        er[(size_t)head * NN + rbase + t] = sEr[t] + bf2f(bA[head]);
    }
}

// ---------------------------------------------------------------------------
// Stage 2: masked softmax over j + PV, flash-style (M_i = lrelu(el_i + max er))
// ---------------------------------------------------------------------------
__global__ __launch_bounds__(256) void attn_kernel(
    const int*   __restrict__ mask,
    const float* __restrict__ Wh,
    const float* __restrict__ el,
    const float* __restrict__ er,
    void*        __restrict__ outv,
    const int*   __restrict__ flagp)
{
    __shared__ float sWh[64 * 64];
    __shared__ float sP[64 * 65];
    __shared__ float sEl[64];
    __shared__ float sM[64];
    __shared__ float sRed[256];

    const int t     = threadIdx.x;
    const int head  = blockIdx.y;
    const int ibase = blockIdx.x * 64;
    const int isbf  = *flagp;

    float m = -3.0e38f;
    for (int j = t; j < NN; j += 256) m = fmaxf(m, er[(size_t)head * NN + j]);
    sRed[t] = m;
    __syncthreads();
    for (int s = 128; s >= 1; s >>= 1) {
        if (t < s) sRed[t] = fmaxf(sRed[t], sRed[t + s]);
        __syncthreads();
    }
    const float Kh = sRed[0];
    if (t < 64) {
        float e = el[(size_t)head * NN + ibase + t];
        sEl[t] = e;
        float x = e + Kh;
        sM[t] = (x >= 0.f) ? x : ALPHA * x;
    }
    __syncthreads();

    const int i0 = (t >> 4) * 4;
    const int o0 = (t & 15) * 4;
    const int jj = t & 63;
    const int ig = t >> 6;

    float acc[4][4];
    float den[4] = {0.f, 0.f, 0.f, 0.f};
#pragma unroll
    for (int a = 0; a < 4; a++)
#pragma unroll
        for (int b = 0; b < 4; b++) acc[a][b] = 0.f;

    for (int j0 = 0; j0 < NN; j0 += 64) {
        const float4* src = (const float4*)(Wh + ((size_t)head * NN + j0) * FOUT);
#pragma unroll
        for (int q = 0; q < 4; q++) ((float4*)sWh)[q * 256 + t] = src[q * 256 + t];

        float erj = er[(size_t)head * NN + j0 + jj];
        const int* mrow = mask + (size_t)ibase * NN + j0;
#pragma unroll
        for (int ii = 0; ii < 16; ii++) {
            int i = ii * 4 + ig;
            int mv = mrow[(size_t)i * NN + jj];
            float s = sEl[i] + erj;
            s = (s >= 0.f) ? s : ALPHA * s;
            sP[i * 65 + jj] = (mv > 0) ? __expf(s - sM[i]) : 0.f;
        }
        __syncthreads();

#pragma unroll 4
        for (int j2 = 0; j2 < 64; j2++) {
            float4 wv = *(const float4*)(sWh + j2 * 64 + o0);
            float p0 = sP[(i0 + 0) * 65 + j2];
            float p1 = sP[(i0 + 1) * 65 + j2];
            float p2 = sP[(i0 + 2) * 65 + j2];
            float p3 = sP[(i0 + 3) * 65 + j2];
            den[0] += p0; den[1] += p1; den[2] += p2; den[3] += p3;
            acc[0][0] = fmaf(p0, wv.x, acc[0][0]);
            acc[0][1] = fmaf(p0, wv.y, acc[0][1]);
            acc[0][2] = fmaf(p0, wv.z, acc[0][2]);
            acc[0][3] = fmaf(p0, wv.w, acc[0][3]);
            acc[1][0] = fmaf(p1, wv.x, acc[1][0]);
            acc[1][1] = fmaf(p1, wv.y, acc[1][1]);
            acc[1][2] = fmaf(p1, wv.z, acc[1][2]);
            acc[1][3] = fmaf(p1, wv.w, acc[1][3]);
            acc[2][0] = fmaf(p2, wv.x, acc[2][0]);
            acc[2][1] = fmaf(p2, wv.y, acc[2][1]);
            acc[2][2] = fmaf(p2, wv.z, acc[2][2]);
            acc[2][3] = fmaf(p2, wv.w, acc[2][3]);
            acc[3][0] = fmaf(p3, wv.x, acc[3][0]);
            acc[3][1] = fmaf(p3, wv.y, acc[3][1]);
            acc[3][2] = fmaf(p3, wv.z, acc[3][2]);
            acc[3][3] = fmaf(p3, wv.w, acc[3][3]);
        }
        __syncthreads();
    }

#pragma unroll
    for (int a = 0; a < 4; a++) {
        float inv = 1.f / den[a];
        float x0 = acc[a][0] * inv; x0 = (x0 > 0.f) ? x0 : __expf(x0) - 1.f;
        float x1 = acc[a][1] * inv; x1 = (x1 > 0.f) ? x1 : __expf(x1) - 1.f;
        float x2 = acc[a][2] * inv; x2 = (x2 > 0.f) ? x2 : __expf(x2) - 1.f;
        float x3 = acc[a][3] * inv; x3 = (x3 > 0.f) ? x3 : __expf(x3) - 1.f;
        size_t idx = (size_t)(ibase + i0 + a) * (NH * FOUT) + head * FOUT + o0;
        if (isbf) {
            ushort4 o4;
            o4.x = f2bf(x0); o4.y = f2bf(x1); o4.z = f2bf(x2); o4.w = f2bf(x3);
            *(ushort4*)((ushort*)outv + idx) = o4;
        } else {
            *(float4*)((float*)outv + idx) = make_float4(x0, x1, x2, x3);
        }
    }
}

extern "C" void kernel_launch(void* const* d_in, const int* in_sizes, int n_in,
                              void* d_out, int out_size, void* d_ws, size_t ws_size,
                              hipStream_t stream)
{
    const void* hraw = d_in[0];
    const int*  mask = (const int*)d_in[1];
    const void* Wraw = d_in[2];
    const void* bWr  = d_in[3];
    const void* alr  = d_in[4];
    const void* arr  = d_in[5];
    const void* bAr  = d_in[6];

    // workspace layout (16B aligned)
    int*    flag = (int*)d_ws;
    ushort* bh   = (ushort*)((char*)d_ws + 16);            // 2,097,152
    ushort* bWm  = bh + (size_t)NN * FIN;                  // 262,144
    ushort* bbW  = bWm + (size_t)NH * FIN * FOUT;          // 512
    ushort* bal  = bbW + NH * FOUT;                        // 512
    ushort* bar  = bal + NH * FOUT;                        // 512
    ushort* bbA  = bar + NH * FOUT;                        // 8 (+pad)
    float*  Wh   = (float*)((char*)d_ws + 16 +
                            2 * ((size_t)NN * FIN + NH * FIN * FOUT + 3 * NH * FOUT + 8));
    float*  el   = Wh + (size_t)NH * NN * FOUT;
    float*  er   = el + (size_t)NH * NN;

    detect_kernel<<<1, 256, 0, stream>>>((const ushort*)hraw, flag);

    int nh_ = NN * FIN, nw_ = NH * FIN * FOUT, nv_ = NH * FOUT;
    convert_kernel<<<(nh_ + 255) / 256, 256, 0, stream>>>(hraw, bh, nh_, flag);
    convert_kernel<<<(nw_ + 255) / 256, 256, 0, stream>>>(Wraw, bWm, nw_, flag);
    convert_kernel<<<(nv_ + 255) / 256, 256, 0, stream>>>(bWr, bbW, nv_, flag);
    convert_kernel<<<(nv_ + 255) / 256, 256, 0, stream>>>(alr, bal, nv_, flag);
    convert_kernel<<<(nv_ + 255) / 256, 256, 0, stream>>>(arr, bar, nv_, flag);
    convert_kernel<<<1, 256, 0, stream>>>(bAr, bbA, NH, flag);

    wh_kernel<<<dim3(NN / 64, NH), 256, 0, stream>>>(bh, bWm, bbW, bal, bar, bbA, Wh, el, er);
    attn_kernel<<<dim3(NN / 64, NH), 256, 0, stream>>>(mask, Wh, el, er, d_out, flag);
}

// Round 3
// 299.095 us; speedup vs baseline: 2.7313x; 2.7313x over previous
//
#include <hip/hip_runtime.h>
#include <hip/hip_bf16.h>

#define NN 4096
#define FIN 512
#define FOUT 64
#define NH 8
#define ALPHA 0.2f

typedef unsigned int uint;
typedef unsigned short ushort;
typedef __attribute__((ext_vector_type(8))) short short8;
typedef __attribute__((ext_vector_type(4))) float floatx4;

__device__ __forceinline__ float bflo(uint u) { return __uint_as_float(u << 16); }
__device__ __forceinline__ float bfhi(uint u) { return __uint_as_float(u & 0xffff0000u); }
__device__ __forceinline__ float bf2f(ushort s) { return __uint_as_float(((uint)s) << 16); }
__device__ __forceinline__ ushort f2bf(float f) {
    uint u = __float_as_uint(f);
    u += 0x7fffu + ((u >> 16) & 1u);   // RNE
    return (ushort)(u >> 16);
}

// ---------------------------------------------------------------------------
// dtype probe (bf16 vs fp32 harness ambiguity) — see round-1 notes
// ---------------------------------------------------------------------------
__global__ void detect_kernel(const ushort* __restrict__ hraw, int* __restrict__ flag) {
    __shared__ int cnt[256];
    int t = threadIdx.x;
    float v = bf2f(hraw[2 * t]);
    float a = fabsf(v);
    cnt[t] = (a >= 1e-3f && a <= 100.0f) ? 1 : 0;
    __syncthreads();
    for (int s = 128; s >= 1; s >>= 1) {
        if (t < s) cnt[t] += cnt[t + s];
        __syncthreads();
    }
    if (t == 0) *flag = (cnt[0] >= 128) ? 1 : 0;
}

__global__ void convert_kernel(const void* __restrict__ src, ushort* __restrict__ dst,
                               int n, const int* __restrict__ flag) {
    int i = blockIdx.x * 256 + threadIdx.x;
    if (i >= n) return;
    if (*flag)
        dst[i] = ((const ushort*)src)[i];
    else
        dst[i] = f2bf(((const float*)src)[i]);
}

// ---------------------------------------------------------------------------
// Stage 1: Wh = h*W + bW (fp32 acc) -> WhT[h][o][n] bf16 (o-major for MFMA B),
//          el[h,n] = Wh.a_l ; er'[h,n] = Wh.a_r + bA
// ---------------------------------------------------------------------------
__global__ __launch_bounds__(256) void wh_kernel(
    const ushort* __restrict__ hmat,   // [N][FIN] bf16
    const ushort* __restrict__ Wmat,   // [H][FIN][FOUT] bf16
    const ushort* __restrict__ bW,
    const ushort* __restrict__ a_l,
    const ushort* __restrict__ a_r,
    const ushort* __restrict__ bA,
    ushort* __restrict__ WhT,          // [H][FOUT][N] bf16
    float* __restrict__ el,
    float* __restrict__ er)
{
    __shared__ uint   sH[64][68];
    __shared__ ushort sW[128][64];
    __shared__ ushort sT[64][72];      // transpose bounce: [row i][col o]
    __shared__ float  sEl[64], sEr[64];

    const int t     = threadIdx.x;
    const int head  = blockIdx.y;
    const int rbase = blockIdx.x * 64;

    const int r0 = (t >> 4) * 4;
    const int c0 = (t & 15) * 4;

    float acc[4][4];
#pragma unroll
    for (int a = 0; a < 4; a++)
#pragma unroll
        for (int b = 0; b < 4; b++) acc[a][b] = 0.f;

    for (int k0 = 0; k0 < FIN; k0 += 128) {
#pragma unroll
        for (int it = 0; it < 4; it++) {
            int id = it * 256 + t;
            int r = id >> 4, q = id & 15;
            uint4 v = *(const uint4*)(hmat + (size_t)(rbase + r) * FIN + k0 + q * 8);
            *(uint4*)(&sH[r][q * 4]) = v;
        }
#pragma unroll
        for (int it = 0; it < 4; it++) {
            int id = it * 256 + t;
            int kk = id >> 3, q = id & 7;
            uint4 v = *(const uint4*)(Wmat + (size_t)head * FIN * FOUT +
                                      (size_t)(k0 + kk) * FOUT + q * 8);
            *(uint4*)(&sW[kk][q * 8]) = v;
        }
        __syncthreads();

#pragma unroll 4
        for (int kp = 0; kp < 64; kp++) {
            uint hv[4] = { sH[r0 + 0][kp], sH[r0 + 1][kp], sH[r0 + 2][kp], sH[r0 + 3][kp] };
            uint2 w0 = *(const uint2*)(&sW[2 * kp + 0][c0]);
            uint2 w1 = *(const uint2*)(&sW[2 * kp + 1][c0]);
            float wA[4] = { bflo(w0.x), bfhi(w0.x), bflo(w0.y), bfhi(w0.y) };
            float wB[4] = { bflo(w1.x), bfhi(w1.x), bflo(w1.y), bfhi(w1.y) };
#pragma unroll
            for (int a = 0; a < 4; a++) {
                float xlo = bflo(hv[a]);
                float xhi = bfhi(hv[a]);
#pragma unroll
                for (int b = 0; b < 4; b++)
                    acc[a][b] = fmaf(xlo, wA[b], fmaf(xhi, wB[b], acc[a][b]));
            }
        }
        __syncthreads();
    }

    float al[4], ar[4], bw[4];
#pragma unroll
    for (int b = 0; b < 4; b++) {
        al[b] = bf2f(a_l[head * FOUT + c0 + b]);
        ar[b] = bf2f(a_r[head * FOUT + c0 + b]);
        bw[b] = bf2f(bW[head * FOUT + c0 + b]);
    }
    float pl[4] = {0.f, 0.f, 0.f, 0.f}, pr[4] = {0.f, 0.f, 0.f, 0.f};
#pragma unroll
    for (int a = 0; a < 4; a++) {
#pragma unroll
        for (int b = 0; b < 4; b++) {
            acc[a][b] += bw[b];
            pl[a] = fmaf(acc[a][b], al[b], pl[a]);
            pr[a] = fmaf(acc[a][b], ar[b], pr[a]);
        }
        // bf16 Wh into transpose bounce
        uint u0 = (uint)f2bf(acc[a][0]) | ((uint)f2bf(acc[a][1]) << 16);
        uint u1 = (uint)f2bf(acc[a][2]) | ((uint)f2bf(acc[a][3]) << 16);
        *(uint*)(&sT[r0 + a][c0])     = u0;
        *(uint*)(&sT[r0 + a][c0 + 2]) = u1;
    }
#pragma unroll
    for (int off = 1; off < 16; off <<= 1) {
#pragma unroll
        for (int a = 0; a < 4; a++) {
            pl[a] += __shfl_xor(pl[a], off);
            pr[a] += __shfl_xor(pr[a], off);
        }
    }
    if ((t & 15) == 0) {
#pragma unroll
        for (int a = 0; a < 4; a++) { sEl[r0 + a] = pl[a]; sEr[r0 + a] = pr[a]; }
    }
    __syncthreads();

    // coalesced WhT store: thread -> o = t>>2, 16 n's
    {
        int o = t >> 2, jh = t & 3;
        uint w[8];
#pragma unroll
        for (int k = 0; k < 8; k++) {
            w[k] = (uint)sT[jh * 16 + 2 * k][o] | ((uint)sT[jh * 16 + 2 * k + 1][o] << 16);
        }
        ushort* dst = WhT + ((size_t)head * FOUT + o) * NN + rbase + jh * 16;
        *(uint4*)dst       = make_uint4(w[0], w[1], w[2], w[3]);
        *(uint4*)(dst + 8) = make_uint4(w[4], w[5], w[6], w[7]);
    }
    if (t < 64) {
        el[(size_t)head * NN + rbase + t] = sEl[t];
        er[(size_t)head * NN + rbase + t] = sEr[t] + bf2f(bA[head]);
    }
}

// ---------------------------------------------------------------------------
// Stage 2 (MFMA): per (head, 64-row tile). P bf16 in LDS (A-op layout),
// Wh tile bf16 in LDS (B-op layout), 16x16x32 MFMA PV + ones-MFMA denominator.
// ---------------------------------------------------------------------------
__global__ __launch_bounds__(256) void attn_kernel(
    const int*    __restrict__ mask,
    const ushort* __restrict__ WhT,    // [H][FOUT][N] bf16
    const float*  __restrict__ el,
    const float*  __restrict__ er,
    void*         __restrict__ outv,
    const int*    __restrict__ flagp)
{
    __shared__ ushort sP[64][72];      // P[i][j] bf16, pad 8 (2-way banks = free)
    __shared__ ushort sV[64][72];      // Wh^T tile [o][j]
    __shared__ float  sEl[64], sM[64], sRed[256];

    const int t     = threadIdx.x;
    const int head  = blockIdx.y;
    const int ibase = blockIdx.x * 64;

    // Kh = max_j er'
    float m = -3.0e38f;
    for (int j = t; j < NN; j += 256) m = fmaxf(m, er[(size_t)head * NN + j]);
    sRed[t] = m;
    __syncthreads();
    for (int s = 128; s >= 1; s >>= 1) {
        if (t < s) sRed[t] = fmaxf(sRed[t], sRed[t + s]);
        __syncthreads();
    }
    const float Kh = sRed[0];
    if (t < 64) {
        float e = el[(size_t)head * NN + ibase + t];
        sEl[t] = e;
        float x = e + Kh;
        sM[t] = (x >= 0.f) ? x : ALPHA * x;
    }
    __syncthreads();

    const int lane = t & 63;
    const int wid  = t >> 6;
    const int i0w  = wid * 16;         // wave's 16-row slab
    const int lm   = lane & 15;
    const int lq   = lane >> 4;

    const short8 ones = {0x3F80, 0x3F80, 0x3F80, 0x3F80, 0x3F80, 0x3F80, 0x3F80, 0x3F80};
    floatx4 C0 = {0.f, 0.f, 0.f, 0.f}, C1 = C0, C2 = C0, C3 = C0, Cd = C0;

    const int pv_o = t >> 2;           // staging row (o)
    const int pv_j = (t & 3) * 16;     // staging col group

    for (int j0 = 0; j0 < NN; j0 += 64) {
        // stage Wh^T tile [o][j] (coalesced 32B/thread)
        {
            const ushort* src = WhT + ((size_t)head * FOUT + pv_o) * NN + j0 + pv_j;
            uint4 v0 = *(const uint4*)src;
            uint4 v1 = *(const uint4*)(src + 8);
            *(uint4*)(&sV[pv_o][pv_j])     = v0;
            *(uint4*)(&sV[pv_o][pv_j + 8]) = v1;
        }
        // P-gen: 2 groups of 8 contiguous j per thread, packed b128 writes
#pragma unroll
        for (int gg = 0; gg < 2; gg++) {
            int g  = gg * 256 + t;
            int i  = g >> 3;
            int j8 = (g & 7) * 8;
            const int* mp = mask + (size_t)(ibase + i) * NN + j0 + j8;
            int4 m0 = *(const int4*)mp;
            int4 m1 = *(const int4*)(mp + 4);
            const float* ep = er + (size_t)head * NN + j0 + j8;
            float4 e0 = *(const float4*)ep;
            float4 e1 = *(const float4*)(ep + 4);
            float eli = sEl[i], Mi = sM[i];
            float s0, p[8];
            s0 = eli + e0.x; s0 = (s0 >= 0.f) ? s0 : ALPHA * s0; p[0] = (m0.x > 0) ? __expf(s0 - Mi) : 0.f;
            s0 = eli + e0.y; s0 = (s0 >= 0.f) ? s0 : ALPHA * s0; p[1] = (m0.y > 0) ? __expf(s0 - Mi) : 0.f;
            s0 = eli + e0.z; s0 = (s0 >= 0.f) ? s0 : ALPHA * s0; p[2] = (m0.z > 0) ? __expf(s0 - Mi) : 0.f;
            s0 = eli + e0.w; s0 = (s0 >= 0.f) ? s0 : ALPHA * s0; p[3] = (m0.w > 0) ? __expf(s0 - Mi) : 0.f;
            s0 = eli + e1.x; s0 = (s0 >= 0.f) ? s0 : ALPHA * s0; p[4] = (m1.x > 0) ? __expf(s0 - Mi) : 0.f;
            s0 = eli + e1.y; s0 = (s0 >= 0.f) ? s0 : ALPHA * s0; p[5] = (m1.y > 0) ? __expf(s0 - Mi) : 0.f;
            s0 = eli + e1.z; s0 = (s0 >= 0.f) ? s0 : ALPHA * s0; p[6] = (m1.z > 0) ? __expf(s0 - Mi) : 0.f;
            s0 = eli + e1.w; s0 = (s0 >= 0.f) ? s0 : ALPHA * s0; p[7] = (m1.w > 0) ? __expf(s0 - Mi) : 0.f;
            uint4 pk;
            pk.x = (uint)f2bf(p[0]) | ((uint)f2bf(p[1]) << 16);
            pk.y = (uint)f2bf(p[2]) | ((uint)f2bf(p[3]) << 16);
            pk.z = (uint)f2bf(p[4]) | ((uint)f2bf(p[5]) << 16);
            pk.w = (uint)f2bf(p[6]) | ((uint)f2bf(p[7]) << 16);
            *(uint4*)(&sP[i][j8]) = pk;
        }
        __syncthreads();

        // MFMA: A = P slab rows i0w..i0w+15, B = Wh^T cols, 2 k-chunks of 32
#pragma unroll
        for (int kc = 0; kc < 2; kc++) {
            short8 a = *(const short8*)(&sP[i0w + lm][kc * 32 + lq * 8]);
            Cd = __builtin_amdgcn_mfma_f32_16x16x32_bf16(a, ones, Cd, 0, 0, 0);
            short8 b0 = *(const short8*)(&sV[0  + lm][kc * 32 + lq * 8]);
            C0 = __builtin_amdgcn_mfma_f32_16x16x32_bf16(a, b0, C0, 0, 0, 0);
            short8 b1 = *(const short8*)(&sV[16 + lm][kc * 32 + lq * 8]);
            C1 = __builtin_amdgcn_mfma_f32_16x16x32_bf16(a, b1, C1, 0, 0, 0);
            short8 b2 = *(const short8*)(&sV[32 + lm][kc * 32 + lq * 8]);
            C2 = __builtin_amdgcn_mfma_f32_16x16x32_bf16(a, b2, C2, 0, 0, 0);
            short8 b3 = *(const short8*)(&sV[48 + lm][kc * 32 + lq * 8]);
            C3 = __builtin_amdgcn_mfma_f32_16x16x32_bf16(a, b3, C3, 0, 0, 0);
        }
        __syncthreads();
    }

    // epilogue: normalize (den in matching C-layout rows), elu, store
    const int isbf = *flagp;
#pragma unroll
    for (int r = 0; r < 4; r++) {
        int row = ibase + i0w + lq * 4 + r;
        float inv = 1.f / Cd[r];
        float x0 = C0[r] * inv; x0 = (x0 > 0.f) ? x0 : __expf(x0) - 1.f;
        float x1 = C1[r] * inv; x1 = (x1 > 0.f) ? x1 : __expf(x1) - 1.f;
        float x2 = C2[r] * inv; x2 = (x2 > 0.f) ? x2 : __expf(x2) - 1.f;
        float x3 = C3[r] * inv; x3 = (x3 > 0.f) ? x3 : __expf(x3) - 1.f;
        size_t base = (size_t)row * (NH * FOUT) + head * FOUT + lm;
        if (isbf) {
            ushort* o = (ushort*)outv;
            o[base + 0]  = f2bf(x0);
            o[base + 16] = f2bf(x1);
            o[base + 32] = f2bf(x2);
            o[base + 48] = f2bf(x3);
        } else {
            float* o = (float*)outv;
            o[base + 0]  = x0;
            o[base + 16] = x1;
            o[base + 32] = x2;
            o[base + 48] = x3;
        }
    }
}

extern "C" void kernel_launch(void* const* d_in, const int* in_sizes, int n_in,
                              void* d_out, int out_size, void* d_ws, size_t ws_size,
                              hipStream_t stream)
{
    const void* hraw = d_in[0];
    const int*  mask = (const int*)d_in[1];
    const void* Wraw = d_in[2];
    const void* bWr  = d_in[3];
    const void* alr  = d_in[4];
    const void* arr  = d_in[5];
    const void* bAr  = d_in[6];

    int*    flag = (int*)d_ws;
    ushort* bh   = (ushort*)((char*)d_ws + 16);
    ushort* bWm  = bh + (size_t)NN * FIN;
    ushort* bbW  = bWm + (size_t)NH * FIN * FOUT;
    ushort* bal  = bbW + NH * FOUT;
    ushort* bar  = bal + NH * FOUT;
    ushort* bbA  = bar + NH * FOUT;
    size_t  off  = 16 + 2 * ((size_t)NN * FIN + (size_t)NH * FIN * FOUT + 3 * NH * FOUT + 8);
    ushort* WhT  = (ushort*)((char*)d_ws + off);                 // 4 MB
    float*  el   = (float*)((char*)d_ws + off + 2 * (size_t)NH * FOUT * NN);
    float*  er   = el + (size_t)NH * NN;

    detect_kernel<<<1, 256, 0, stream>>>((const ushort*)hraw, flag);

    int nh_ = NN * FIN, nw_ = NH * FIN * FOUT, nv_ = NH * FOUT;
    convert_kernel<<<(nh_ + 255) / 256, 256, 0, stream>>>(hraw, bh, nh_, flag);
    convert_kernel<<<(nw_ + 255) / 256, 256, 0, stream>>>(Wraw, bWm, nw_, flag);
    convert_kernel<<<(nv_ + 255) / 256, 256, 0, stream>>>(bWr, bbW, nv_, flag);
    convert_kernel<<<(nv_ + 255) / 256, 256, 0, stream>>>(alr, bal, nv_, flag);
    convert_kernel<<<(nv_ + 255) / 256, 256, 0, stream>>>(arr, bar, nv_, flag);
    convert_kernel<<<1, 256, 0, stream>>>(bAr, bbA, NH, flag);

    wh_kernel<<<dim3(NN / 64, NH), 256, 0, stream>>>(bh, bWm, bbW, bal, bar, bbA, WhT, el, er);
    attn_kernel<<<dim3(NN / 64, NH), 256, 0, stream>>>(mask, WhT, el, er, d_out, flag);
}

// Round 4
// 293.810 us; speedup vs baseline: 2.7805x; 1.0180x over previous
//
#include <hip/hip_runtime.h>
#include <hip/hip_bf16.h>

#define NN 4096
#define FIN 512
#define FOUT 64
#define NH 8
#define ALPHA 0.2f

typedef unsigned int uint;
typedef unsigned short ushort;
typedef unsigned char uchar;
typedef unsigned long long ull;
typedef __attribute__((ext_vector_type(8))) short short8;
typedef __attribute__((ext_vector_type(4))) float floatx4;

__device__ __forceinline__ float bf2f(ushort s) { return __uint_as_float(((uint)s) << 16); }
__device__ __forceinline__ ushort f2bf(float f) {
    uint u = __float_as_uint(f);
    u += 0x7fffu + ((u >> 16) & 1u);   // RNE
    return (ushort)(u >> 16);
}
__device__ __forceinline__ short8 u4s8(uint4 v) {
    union { uint4 u; short8 s; } x; x.u = v; return x.s;
}

// ---------------------------------------------------------------------------
// dtype probe (bf16 vs fp32 harness ambiguity)
// ---------------------------------------------------------------------------
__global__ void detect_kernel(const ushort* __restrict__ hraw, int* __restrict__ flag) {
    __shared__ int cnt[256];
    int t = threadIdx.x;
    float v = bf2f(hraw[2 * t]);
    float a = fabsf(v);
    cnt[t] = (a >= 1e-3f && a <= 100.0f) ? 1 : 0;
    __syncthreads();
    for (int s = 128; s >= 1; s >>= 1) {
        if (t < s) cnt[t] += cnt[t + s];
        __syncthreads();
    }
    if (t == 0) *flag = (cnt[0] >= 128) ? 1 : 0;
}

__global__ void convert_kernel(const void* __restrict__ src, ushort* __restrict__ dst,
                               int n, const int* __restrict__ flag) {
    int i = blockIdx.x * 256 + threadIdx.x;
    if (i >= n) return;
    if (*flag)
        dst[i] = ((const ushort*)src)[i];
    else
        dst[i] = f2bf(((const float*)src)[i]);
}

// W[h][k][o] -> WT[h][o][k] bf16 (B-operand layout: k-contiguous)
__global__ void transw_kernel(const void* __restrict__ Wraw, ushort* __restrict__ WT,
                              const int* __restrict__ flag) {
    int h = blockIdx.x >> 2, kq = blockIdx.x & 3;
    int o = threadIdx.x & 63, sub = threadIdx.x >> 6;
    int kbase = kq * 128 + sub * 32;
    int isbf = *flag;
    uint pk[16];
#pragma unroll
    for (int kk = 0; kk < 32; kk += 2) {
        float v0, v1;
        size_t s0 = ((size_t)h * FIN + kbase + kk) * FOUT + o;
        size_t s1 = s0 + FOUT;
        if (isbf) { v0 = bf2f(((const ushort*)Wraw)[s0]); v1 = bf2f(((const ushort*)Wraw)[s1]); }
        else      { v0 = ((const float*)Wraw)[s0];        v1 = ((const float*)Wraw)[s1]; }
        pk[kk >> 1] = (uint)f2bf(v0) | ((uint)f2bf(v1) << 16);
    }
    ushort* dst = WT + ((size_t)h * FOUT + o) * FIN + kbase;
#pragma unroll
    for (int q = 0; q < 4; q++)
        *(uint4*)(dst + q * 8) = make_uint4(pk[q * 4], pk[q * 4 + 1], pk[q * 4 + 2], pk[q * 4 + 3]);
}

// mask int32 [NN][NN] -> bitmask, 1 bit per entry (little-endian per 64-j word)
__global__ void packmask_kernel(const int* __restrict__ mask, ull* __restrict__ mb) {
    int idx = blockIdx.x * 256 + threadIdx.x;
    int v = mask[idx];
    ull b = __ballot(v > 0);
    if ((threadIdx.x & 63) == 0) mb[idx >> 6] = b;
}

// per-head max of er' (softmax bound helper)
__global__ void kh_kernel(const float* __restrict__ er, float* __restrict__ Kh) {
    __shared__ float red[256];
    int h = blockIdx.x, t = threadIdx.x;
    float m = -3.0e38f;
    for (int j = t; j < NN; j += 256) m = fmaxf(m, er[(size_t)h * NN + j]);
    red[t] = m;
    __syncthreads();
    for (int s = 128; s >= 1; s >>= 1) {
        if (t < s) red[t] = fmaxf(red[t], red[t + s]);
        __syncthreads();
    }
    if (t == 0) Kh[h] = red[0];
}

// ---------------------------------------------------------------------------
// Stage 1 (MFMA, zero-LDS main loop): Wh = h*W + bW; WhT[h][o][n] bf16;
// el = Wh.a_l ; er' = Wh.a_r + bA
// ---------------------------------------------------------------------------
__global__ __launch_bounds__(256) void wh_kernel(
    const ushort* __restrict__ hmat,   // [N][FIN] bf16
    const ushort* __restrict__ WT,     // [H][FOUT][FIN] bf16
    const void* __restrict__ bWr, const void* __restrict__ alr,
    const void* __restrict__ arr, const void* __restrict__ bAr,
    const int* __restrict__ flag,
    ushort* __restrict__ WhT,          // [H][FOUT][N] bf16
    float* __restrict__ el, float* __restrict__ er)
{
    __shared__ __align__(16) ushort sT[64][72];   // [o][i_loc] bounce for coalesced WhT store
    const int t = threadIdx.x, lane = t & 63, wid = t >> 6;
    const int head = blockIdx.y, rbase = blockIdx.x * 64;
    const int lm = lane & 15, lq = lane >> 4;

    floatx4 C[4];
#pragma unroll
    for (int cg = 0; cg < 4; cg++) C[cg] = (floatx4){0.f, 0.f, 0.f, 0.f};

    const ushort* Ap = hmat + (size_t)(rbase + wid * 16 + lm) * FIN + lq * 8;
    const ushort* Bp = WT + (size_t)head * FOUT * FIN + (size_t)lm * FIN + lq * 8;

#pragma unroll
    for (int kc = 0; kc < 16; kc++) {
        short8 a = *(const short8*)(Ap + kc * 32);
#pragma unroll
        for (int cg = 0; cg < 4; cg++) {
            short8 b = *(const short8*)(Bp + (size_t)cg * 16 * FIN + kc * 32);
            C[cg] = __builtin_amdgcn_mfma_f32_16x16x32_bf16(a, b, C[cg], 0, 0, 0);
        }
    }

    // epilogue: bias, el/er dots, bf16 WhT via LDS transpose bounce
    const int isbf = *flag;
    float bA = isbf ? bf2f(((const ushort*)bAr)[head]) : ((const float*)bAr)[head];
    float pel[4] = {0.f, 0.f, 0.f, 0.f}, per[4] = {0.f, 0.f, 0.f, 0.f};
#pragma unroll
    for (int cg = 0; cg < 4; cg++) {
        int o = head * FOUT + cg * 16 + lm;
        float bw = isbf ? bf2f(((const ushort*)bWr)[o]) : ((const float*)bWr)[o];
        float av = isbf ? bf2f(((const ushort*)alr)[o]) : ((const float*)alr)[o];
        float rv = isbf ? bf2f(((const ushort*)arr)[o]) : ((const float*)arr)[o];
        ushort pk[4];
#pragma unroll
        for (int r = 0; r < 4; r++) {
            float v = C[cg][r] + bw;
            pel[r] += v * av;
            per[r] += v * rv;
            pk[r] = f2bf(v);
        }
        ushort4 p4; p4.x = pk[0]; p4.y = pk[1]; p4.z = pk[2]; p4.w = pk[3];
        *(ushort4*)(&sT[cg * 16 + lm][wid * 16 + lq * 4]) = p4;
    }
#pragma unroll
    for (int off = 1; off < 16; off <<= 1) {
#pragma unroll
        for (int r = 0; r < 4; r++) {
            pel[r] += __shfl_xor(pel[r], off);
            per[r] += __shfl_xor(per[r], off);
        }
    }
    if (lm == 0) {
#pragma unroll
        for (int r = 0; r < 4; r++) {
            int row = rbase + wid * 16 + lq * 4 + r;
            el[(size_t)head * NN + row] = pel[r];
            er[(size_t)head * NN + row] = per[r] + bA;
        }
    }
    __syncthreads();
    {
        int o = t >> 2, ch = t & 3;
        uint4 v0 = *(const uint4*)(&sT[o][ch * 16]);
        uint4 v1 = *(const uint4*)(&sT[o][ch * 16 + 8]);
        ushort* d = WhT + ((size_t)head * FOUT + o) * NN + rbase + ch * 16;
        *(uint4*)d = v0;
        *(uint4*)(d + 8) = v1;
    }
}

// ---------------------------------------------------------------------------
// Stage 2: i-tile 32, ping-pong P buffer, 1 barrier/iter, B-frags from global
// ---------------------------------------------------------------------------
__device__ __forceinline__ void pgen(uint mby, float4 e0, float4 e1,
                                     float eli, float Mi, ushort* dst) {
    float ev[8] = {e0.x, e0.y, e0.z, e0.w, e1.x, e1.y, e1.z, e1.w};
    float p[8];
#pragma unroll
    for (int k = 0; k < 8; k++) {
        float s = eli + ev[k];
        s = fmaxf(s, ALPHA * s);      // leaky_relu (alpha<1)
        s = s - Mi;
        s = ((mby >> k) & 1u) ? s : -100.f;
        p[k] = __expf(s);
    }
    uint4 o;
    o.x = (uint)f2bf(p[0]) | ((uint)f2bf(p[1]) << 16);
    o.y = (uint)f2bf(p[2]) | ((uint)f2bf(p[3]) << 16);
    o.z = (uint)f2bf(p[4]) | ((uint)f2bf(p[5]) << 16);
    o.w = (uint)f2bf(p[6]) | ((uint)f2bf(p[7]) << 16);
    *(uint4*)dst = o;
}

__global__ __launch_bounds__(256) void attn_kernel(
    const uchar* __restrict__ mb,      // [NN][512] bitmask
    const ushort* __restrict__ WhT,    // [H][FOUT][NN] bf16
    const float* __restrict__ el, const float* __restrict__ er,
    const float* __restrict__ Kh,
    void* __restrict__ outv, const int* __restrict__ flagp)
{
    __shared__ __align__(16) ushort sP[2][32 * 72];   // ping-pong P tiles

    const int t = threadIdx.x, lane = t & 63, wid = t >> 6;
    const int head = blockIdx.y, ibase = blockIdx.x * 32;
    const int lm = lane & 15, lq = lane >> 4;
    const int s = wid >> 1, c = wid & 1;              // row slab / col half

    // P-gen per-thread constants
    const int pi = t >> 3, pj = t & 7;
    const float eli = el[(size_t)head * NN + ibase + pi];
    float Mi;
    { float x = eli + Kh[head]; Mi = fmaxf(x, ALPHA * x); }
    const uchar* mbp = mb + (size_t)(ibase + pi) * 512 + pj;
    const float* erp = er + (size_t)head * NN + pj * 8;
    const int pofs = pi * 72 + pj * 8;

    const short8 ones = {0x3F80, 0x3F80, 0x3F80, 0x3F80, 0x3F80, 0x3F80, 0x3F80, 0x3F80};
    floatx4 C0 = {0.f, 0.f, 0.f, 0.f}, C1 = C0, Cd = C0;

    const ushort* B0 = WhT + ((size_t)head * FOUT + c * 32 + lm) * NN;
    const ushort* B1 = B0 + (size_t)16 * NN;
    const int aofs = (s * 16 + lm) * 72 + lq * 8;

    // prologue: P(0), prefetch inputs(1)
    uint mby = mbp[0];
    float4 e0 = *(const float4*)(erp);
    float4 e1 = *(const float4*)(erp + 4);
    pgen(mby, e0, e1, eli, Mi, &sP[0][pofs]);
    mby = mbp[8];
    e0 = *(const float4*)(erp + 64);
    e1 = *(const float4*)(erp + 68);
    __syncthreads();

    for (int it = 0; it < 64; it++) {
        const int j0 = it * 64;
        const ushort* cur = sP[it & 1];
        ushort* nxt = &sP[(it + 1) & 1][pofs];

        // issue B loads for this tile (global, L1/L2-hot)
        uint4 b00 = *(const uint4*)(B0 + j0 + lq * 8);
        uint4 b01 = *(const uint4*)(B0 + j0 + 32 + lq * 8);
        uint4 b10 = *(const uint4*)(B1 + j0 + lq * 8);
        uint4 b11 = *(const uint4*)(B1 + j0 + 32 + lq * 8);

        // P-gen for next tile (overlaps B-load latency)
        if (it < 63) pgen(mby, e0, e1, eli, Mi, nxt);
        // prefetch inputs for tile it+2
        if (it < 62) {
            mby = mbp[(it + 2) * 8];
            e0 = *(const float4*)(erp + (it + 2) * 64);
            e1 = *(const float4*)(erp + (it + 2) * 64 + 4);
        }

        // MFMA phase on current tile
        short8 a0 = *(const short8*)(cur + aofs);
        Cd = __builtin_amdgcn_mfma_f32_16x16x32_bf16(a0, ones, Cd, 0, 0, 0);
        C0 = __builtin_amdgcn_mfma_f32_16x16x32_bf16(a0, u4s8(b00), C0, 0, 0, 0);
        C1 = __builtin_amdgcn_mfma_f32_16x16x32_bf16(a0, u4s8(b10), C1, 0, 0, 0);
        short8 a1 = *(const short8*)(cur + aofs + 32);
        Cd = __builtin_amdgcn_mfma_f32_16x16x32_bf16(a1, ones, Cd, 0, 0, 0);
        C0 = __builtin_amdgcn_mfma_f32_16x16x32_bf16(a1, u4s8(b01), C0, 0, 0, 0);
        C1 = __builtin_amdgcn_mfma_f32_16x16x32_bf16(a1, u4s8(b11), C1, 0, 0, 0);
        __syncthreads();
    }

    // epilogue: normalize, elu, store
    const int isbf = *flagp;
#pragma unroll
    for (int r = 0; r < 4; r++) {
        int row = ibase + s * 16 + lq * 4 + r;
        float inv = 1.f / Cd[r];
        float x0 = C0[r] * inv; x0 = (x0 > 0.f) ? x0 : __expf(x0) - 1.f;
        float x1 = C1[r] * inv; x1 = (x1 > 0.f) ? x1 : __expf(x1) - 1.f;
        size_t base = (size_t)row * (NH * FOUT) + head * FOUT + c * 32 + lm;
        if (isbf) {
            ((ushort*)outv)[base]      = f2bf(x0);
            ((ushort*)outv)[base + 16] = f2bf(x1);
        } else {
            ((float*)outv)[base]      = x0;
            ((float*)outv)[base + 16] = x1;
        }
    }
}

extern "C" void kernel_launch(void* const* d_in, const int* in_sizes, int n_in,
                              void* d_out, int out_size, void* d_ws, size_t ws_size,
                              hipStream_t stream)
{
    const void* hraw = d_in[0];
    const int*  mask = (const int*)d_in[1];
    const void* Wraw = d_in[2];
    const void* bWr  = d_in[3];
    const void* alr  = d_in[4];
    const void* arr  = d_in[5];
    const void* bAr  = d_in[6];

    // workspace layout (16B aligned blocks)
    char* w = (char*)d_ws;
    int*    flag = (int*)w;                     w += 16;
    ushort* bh   = (ushort*)w;                  w += (size_t)NN * FIN * 2;        // 4 MB
    ushort* WT   = (ushort*)w;                  w += (size_t)NH * FOUT * FIN * 2; // 512 KB
    ushort* WhT  = (ushort*)w;                  w += (size_t)NH * FOUT * NN * 2;  // 4 MB
    float*  el   = (float*)w;                   w += (size_t)NH * NN * 4;         // 128 KB
    float*  er   = (float*)w;                   w += (size_t)NH * NN * 4;         // 128 KB
    float*  Kh   = (float*)w;                   w += 64;
    uchar*  mb   = (uchar*)w;                   w += (size_t)NN * 512;            // 2 MB

    detect_kernel<<<1, 256, 0, stream>>>((const ushort*)hraw, flag);

    int nh_ = NN * FIN;
    convert_kernel<<<(nh_ + 255) / 256, 256, 0, stream>>>(hraw, bh, nh_, flag);
    transw_kernel<<<32, 256, 0, stream>>>(Wraw, WT, flag);
    packmask_kernel<<<(NN * NN) / 256, 256, 0, stream>>>(mask, (ull*)mb);

    wh_kernel<<<dim3(NN / 64, NH), 256, 0, stream>>>(bh, WT, bWr, alr, arr, bAr, flag,
                                                     WhT, el, er);
    kh_kernel<<<NH, 256, 0, stream>>>(er, Kh);
    attn_kernel<<<dim3(NN / 32, NH), 256, 0, stream>>>(mb, WhT, el, er, Kh, d_out, flag);
}